// Round 6
// baseline (281.535 us; speedup 1.0000x reference)
//
#include <hip/hip_runtime.h>

// MyLSTM: 2-layer LSTM (input=3, hidden=4) + MLP head (4->4 tanh -> 1), B=4096, T=1024.
//
// R6: 2-stage wave pipeline (back to R3's best-measured topology) with TRANS-PACKING.
// Port-model from R2-R5 counters: wall ~= issued port-cycles x ~1.5; wave64 v_exp/v_rcp
// are quarter-rate (16 port-cycles each) and dominate. So cut trans OPS:
//   wave A: layer-0 LSTM (4 trans/step)  -> unchanged from R3.
//   wave B: layer-1 LSTM + head, with the head lagged ONE step inside B's stream:
//     at step s, B computes zp(s-1) BEFORE the cell update, then packs
//     tanh(c1(s)) [lanes rho<2] and tanh(zp(s-1)) [lanes rho>=2] into ONE
//     exp+rcp event. B: 6 trans -> 4 trans; busy ~176c -> ~148c, balancing A (~114c).
// h1 is re-broadcast from rho0 via quad_perm after the packed event; the head's
// sum over units uses row_ror:4/8 (rho-preserving rotations within the 16-lane group).
// Stage assignment is blockIdx-parity-flipped so co-resident blocks put one A and one
// B wave on each SIMD instead of two of the same kind.
//
// Lane layout per 16-lane chain group: unit u=(l>>2)&3, role rho=l&3 (0=i,1=f,2=g,3=o);
// gate row r = rho*4+u. Cross-lane traffic is DPP only. Ring: replicated xor-order
// h0 quad {h0,h0^1,h0^2,h0^3} as one float4/lane (1-op write, b128 read).

#define T_STEPS 1024
#define BATCH   4096
#define CHUNK   16
#define NCHUNK  (T_STEPS / CHUNK)

__device__ __forceinline__ float fast_exp2(float x) {
#if __has_builtin(__builtin_amdgcn_exp2f)
    return __builtin_amdgcn_exp2f(x);
#else
    return exp2f(x);
#endif
}

__device__ __forceinline__ float fast_rcp(float x) {
#if __has_builtin(__builtin_amdgcn_rcpf)
    return __builtin_amdgcn_rcpf(x);
#else
    return 1.0f / x;
#endif
}

// tanh(x) = 2*sigmoid(2x) - 1 = 2/(1+exp2(-2.885390x)) - 1
__device__ __forceinline__ float fast_tanh(float x) {
    return 2.0f * fast_rcp(1.0f + fast_exp2(-2.88539008f * x)) - 1.0f;
}

template <int CTRL>
__device__ __forceinline__ float dpp_mov(float v) {
    int i = __builtin_bit_cast(int, v);
    i = __builtin_amdgcn_mov_dpp(i, CTRL, 0xF, 0xF, true);
    return __builtin_bit_cast(float, i);
}

#define DPP_QB0         0x00   // quad_perm [0,0,0,0] -> i gate / rho0 broadcast
#define DPP_QB1         0x55   // quad_perm [1,1,1,1] -> f gate
#define DPP_QB2         0xAA   // quad_perm [2,2,2,2] -> g gate / rho2 broadcast
#define DPP_QB3         0xFF   // quad_perm [3,3,3,3] -> o gate
#define DPP_ROR4        0x124  // row_ror:4  -> u-1 (rho preserved)
#define DPP_ROR8        0x128  // row_ror:8  -> u^2 (rho preserved)
#define DPP_MIRROR      0x140  // l^15 -> u^3 on quad-uniform data
#define DPP_HALF_MIRROR 0x141  // l^7  -> u^1 on quad-uniform data

__global__ __launch_bounds__(128) void lstm_packed_kernel(
    const float* __restrict__ x,
    const float* __restrict__ W_ih0, const float* __restrict__ W_hh0,
    const float* __restrict__ b_ih0, const float* __restrict__ b_hh0,
    const float* __restrict__ W_ih1, const float* __restrict__ W_hh1,
    const float* __restrict__ b_ih1, const float* __restrict__ b_hh1,
    const float* __restrict__ W1, const float* __restrict__ b1,
    const float* __restrict__ W2, const float* __restrict__ b2,
    float* __restrict__ out)
{
    // h0 ring: [2 slots][16 steps][64 lanes] float4 = 32 KB (replicated xor-order quad)
    __shared__ float4 ring[2][CHUNK][64];

    const int tid  = threadIdx.x;
    const int wave = tid >> 6;
    const int stg  = (wave + blockIdx.x) & 1;   // parity-flip: mixes A/B waves per SIMD
    const int lane = tid & 63;
    const int idx  = lane & 15;         // lane within 16-lane chain group
    const int rho  = lane & 3;          // role: 0=i,1=f,2=g,3=o
    const int u    = (lane >> 2) & 3;   // hidden unit
    const int r    = rho * 4 + u;       // gate row in 16-row weight matrices
    const int ch   = lane >> 4;         // chain within block
    const int batch = blockIdx.x * 4 + ch;
    const bool hiHalf = (rho >= 2);     // pack selector (loop-invariant mask)

    // Per-lane activation constants: role g (rho==2) uses tanh = 2*sigma(2x)-1.
    const float am = (rho == 2) ? -2.88539008f : -1.44269504f;
    const float aa = (rho == 2) ? 2.0f : 1.0f;
    const float ab = (rho == 2) ? -1.0f : 0.0f;

    // ---- stage A (layer 0) constants ----
    const float wx0 = W_ih0[r * 3 + 0];
    const float wx1 = W_ih0[r * 3 + 1];
    const float wx2 = W_ih0[r * 3 + 2];
    const float bias0 = b_ih0[r] + b_hh0[r];
    float wh0[4];
#pragma unroll
    for (int k = 0; k < 4; ++k) wh0[k] = W_hh0[r * 4 + (u ^ k)];   // xor order

    // ---- stage B (layer 1 + head) constants ----
    const float bias1 = b_ih1[r] + b_hh1[r];
    float wi1[4], wh1[4], w1p[4];
#pragma unroll
    for (int k = 0; k < 4; ++k) {
        wi1[k] = W_ih1[r * 4 + (u ^ k)];   // xor order (ring quad is xor-ordered)
        wh1[k] = W_hh1[r * 4 + (u ^ k)];   // xor order (register quad)
        w1p[k] = W1[u * 4 + (u ^ k)];      // xor order (register quad)
    }
    const float b1u = b1[u];
    const float w2u = W2[u];
    const float b2v = b2[0];

    // ---- per-stage state ----
    float h0 = 0.f, c0 = 0.f, h0b = 0.f, h0c = 0.f, h0d = 0.f;   // A
    float h1 = 0.f, c1 = 0.f, h1b = 0.f, h1c = 0.f, h1d = 0.f;   // B
    float ysave = 0.f;                                            // B
    float* op = out + (size_t)batch * T_STEPS;

    const float* xp = x + (size_t)batch * T_STEPS * 3;
    float ax0 = 0.f, ax1 = 0.f, ax2 = 0.f, bx0 = 0.f, bx1 = 0.f, bx2 = 0.f;
    if (stg == 0) {   // prime 2-deep x prefetch
        ax0 = xp[0]; ax1 = xp[1]; ax2 = xp[2];
        bx0 = xp[3]; bx1 = xp[4]; bx2 = xp[5];
        xp += 6;
    }

    for (int c = 0; c < NCHUNK; ++c) {
        if (stg == 0) {
            // ================= stage A: layer 0, chunk c =================
            float4* rg = &ring[c & 1][0][lane];
#pragma unroll
            for (int tt = 0; tt < CHUNK; ++tt) {
                const int t = c * CHUNK + tt;
                const float x0 = ax0, x1 = ax1, x2 = ax2;
                ax0 = bx0; ax1 = bx1; ax2 = bx2;
                const float* xl = (t < T_STEPS - 2) ? xp : (xp - 6);  // clamped tail
                bx0 = xl[0]; bx1 = xl[1]; bx2 = xl[2];
                xp += 3;

                float pre0 = bias0 + wx0 * x0 + wx1 * x1 + wx2 * x2
                           + wh0[0] * h0 + wh0[1] * h0b + wh0[2] * h0c + wh0[3] * h0d;
                float a0 = aa * fast_rcp(1.0f + fast_exp2(am * pre0)) + ab;
                float gi = dpp_mov<DPP_QB0>(a0);
                float gf = dpp_mov<DPP_QB1>(a0);
                float gg = dpp_mov<DPP_QB2>(a0);
                float go = dpp_mov<DPP_QB3>(a0);
                c0 = gf * c0 + gi * gg;
                h0 = go * fast_tanh(c0);
                h0b = dpp_mov<DPP_HALF_MIRROR>(h0);
                h0c = dpp_mov<DPP_ROR8>(h0);
                h0d = dpp_mov<DPP_MIRROR>(h0);

                rg[tt * 64] = make_float4(h0, h0b, h0c, h0d);
            }
        } else if (c >= 1) {
            // ========== stage B: layer 1 (step s) + head (step s-1), chunk c-1 ==========
            const int cc = c - 1;
            const float4* rg = &ring[cc & 1][0][lane];
            float4 hcur = rg[0];
#pragma unroll
            for (int tt = 0; tt < CHUNK; ++tt) {
                float4 hnxt = rg[((tt < CHUNK - 1) ? tt + 1 : tt) * 64];

                // head dot for step s-1: uses h1 state BEFORE this step's update
                float zp = b1u + w1p[0] * h1 + w1p[1] * h1b + w1p[2] * h1c + w1p[3] * h1d;

                // layer-1 gates for step s
                float pre1 = bias1
                           + wi1[0] * hcur.x + wi1[1] * hcur.y
                           + wi1[2] * hcur.z + wi1[3] * hcur.w
                           + wh1[0] * h1 + wh1[1] * h1b + wh1[2] * h1c + wh1[3] * h1d;
                float a1 = aa * fast_rcp(1.0f + fast_exp2(am * pre1)) + ab;
                float gi1 = dpp_mov<DPP_QB0>(a1);
                float gf1 = dpp_mov<DPP_QB1>(a1);
                float gg1 = dpp_mov<DPP_QB2>(a1);
                float go1 = dpp_mov<DPP_QB3>(a1);
                float c1n = gf1 * c1 + gi1 * gg1;

                // PACKED tanh event: rho<2 -> tanh(c1(s)); rho>=2 -> tanh(zp(s-1))
                float pv = hiHalf ? zp : c1n;
                float th = fast_tanh(pv);

                // h1 update: correct at rho0 -> broadcast, then replicate across units
                float h1n = go1 * th;
                float h1q = dpp_mov<DPP_QB0>(h1n);
                h1  = h1q;
                h1b = dpp_mov<DPP_HALF_MIRROR>(h1q);
                h1c = dpp_mov<DPP_ROR8>(h1q);
                h1d = dpp_mov<DPP_MIRROR>(h1q);
                c1 = c1n;

                // y(s-1): z = th at rho>=2; sum over units via rho-preserving rotations
                float yv = w2u * th;
                float t1 = yv + dpp_mov<DPP_ROR8>(yv);
                float y4 = t1 + dpp_mov<DPP_ROR4>(t1);        // full unit sum at rho 2,3
                float y  = dpp_mov<DPP_QB2>(y4) + b2v;        // broadcast rho2 to all lanes

                // stage y(s-1) into lane (s-1)&15; flush completed 16-block at tt==0
                ysave = (((tt + 15) & 15) == idx) ? y : ysave;
                if (tt == 0 && cc >= 1) {
                    op[(cc - 1) * CHUNK + idx] = ysave;   // coalesced 16 floats/chain
                }
                hcur = hnxt;
            }
        }
        __syncthreads();
    }

    if (stg == 1) {
        // drain chunk NCHUNK-1 (same body as above, cc = NCHUNK-1)
        const int cc = NCHUNK - 1;
        const float4* rg = &ring[cc & 1][0][lane];
        float4 hcur = rg[0];
#pragma unroll
        for (int tt = 0; tt < CHUNK; ++tt) {
            float4 hnxt = rg[((tt < CHUNK - 1) ? tt + 1 : tt) * 64];

            float zp = b1u + w1p[0] * h1 + w1p[1] * h1b + w1p[2] * h1c + w1p[3] * h1d;
            float pre1 = bias1
                       + wi1[0] * hcur.x + wi1[1] * hcur.y
                       + wi1[2] * hcur.z + wi1[3] * hcur.w
                       + wh1[0] * h1 + wh1[1] * h1b + wh1[2] * h1c + wh1[3] * h1d;
            float a1 = aa * fast_rcp(1.0f + fast_exp2(am * pre1)) + ab;
            float gi1 = dpp_mov<DPP_QB0>(a1);
            float gf1 = dpp_mov<DPP_QB1>(a1);
            float gg1 = dpp_mov<DPP_QB2>(a1);
            float go1 = dpp_mov<DPP_QB3>(a1);
            float c1n = gf1 * c1 + gi1 * gg1;

            float pv = hiHalf ? zp : c1n;
            float th = fast_tanh(pv);

            float h1n = go1 * th;
            float h1q = dpp_mov<DPP_QB0>(h1n);
            h1  = h1q;
            h1b = dpp_mov<DPP_HALF_MIRROR>(h1q);
            h1c = dpp_mov<DPP_ROR8>(h1q);
            h1d = dpp_mov<DPP_MIRROR>(h1q);
            c1 = c1n;

            float yv = w2u * th;
            float t1 = yv + dpp_mov<DPP_ROR8>(yv);
            float y4 = t1 + dpp_mov<DPP_ROR4>(t1);
            float y  = dpp_mov<DPP_QB2>(y4) + b2v;

            ysave = (((tt + 15) & 15) == idx) ? y : ysave;
            if (tt == 0) {
                op[(cc - 1) * CHUNK + idx] = ysave;
            }
            hcur = hnxt;
        }

        // epilogue: head for the final step s=1023 (uses final h1 state), then flush
        {
            float zp = b1u + w1p[0] * h1 + w1p[1] * h1b + w1p[2] * h1c + w1p[3] * h1d;
            float th = fast_tanh(zp);
            float yv = w2u * th;
            float t1 = yv + dpp_mov<DPP_ROR8>(yv);
            float y4 = t1 + dpp_mov<DPP_ROR4>(t1);
            float y  = dpp_mov<DPP_QB2>(y4) + b2v;
            ysave = (15 == idx) ? y : ysave;
            op[(NCHUNK - 1) * CHUNK + idx] = ysave;
        }
    }
}

extern "C" void kernel_launch(void* const* d_in, const int* in_sizes, int n_in,
                              void* d_out, int out_size, void* d_ws, size_t ws_size,
                              hipStream_t stream) {
    const float* x     = (const float*)d_in[0];
    const float* W_ih0 = (const float*)d_in[1];
    const float* W_hh0 = (const float*)d_in[2];
    const float* b_ih0 = (const float*)d_in[3];
    const float* b_hh0 = (const float*)d_in[4];
    const float* W_ih1 = (const float*)d_in[5];
    const float* W_hh1 = (const float*)d_in[6];
    const float* b_ih1 = (const float*)d_in[7];
    const float* b_hh1 = (const float*)d_in[8];
    const float* W1    = (const float*)d_in[9];
    const float* b1    = (const float*)d_in[10];
    const float* W2    = (const float*)d_in[11];
    const float* b2    = (const float*)d_in[12];
    float* out = (float*)d_out;

    dim3 grid(BATCH / 4);    // 1024 blocks, 4 chains each
    dim3 block(128);         // 2 waves: stage A (layer 0) + stage B (layer 1 + head)
    lstm_packed_kernel<<<grid, block, 0, stream>>>(
        x, W_ih0, W_hh0, b_ih0, b_hh0, W_ih1, W_hh1, b_ih1, b_hh1,
        W1, b1, W2, b2, out);
}

// Round 7
// 252.444 us; speedup vs baseline: 1.1152x; 1.1152x over previous
//
#include <hip/hip_runtime.h>

// MyLSTM: 2-layer LSTM (input=3, hidden=4) + MLP head (4->4 tanh -> 1), B=4096, T=1024.
//
// R7 = R3 (best measured: 206 us) with structural stall fixes, identical cell math:
//  (1) block=512, 8 waves: stage = wave>>2 (0=L0, 1=L1+head), pair = wave&3.
//      With the HW's wave%4 SIMD round-robin, every SIMD gets exactly one A-wave and
//      one B-wave (R3's 128-thread blocks paired A/B per SIMD only by luck).
//  (2) x is chunk-staged through LDS: per chunk, each A-lane loads 12B (coalesced,
//      step idx of its chain) + one ds_write_b128; per step ONE broadcast ds_read_b128
//      (1-step prefetched, +17 pad -> conflict-free). Removes all per-step global
//      loads, vmcnt jitter, and tail-clamp pointer cndmasks from the hot loop.
//  (3) slim plain-order h0 ring (rho0 lanes write h0[u] scalar; B reads b128 broadcast,
//      plain-order wi1), B prefetches the ring 2 steps deep.
// R4/R6 lessons honored: no in-stream stage merging, no trans packing (both lengthened
// serial chains and regressed). Cross-lane traffic is DPP only.
//
// Lane layout per 16-lane chain group: unit u=(l>>2)&3, role rho=l&3 (0=i,1=f,2=g,3=o);
// gate row r = rho*4+u.

#define T_STEPS 1024
#define BATCH   4096
#define CHUNK   16
#define NCHUNK  (T_STEPS / CHUNK)

__device__ __forceinline__ float fast_exp2(float x) {
#if __has_builtin(__builtin_amdgcn_exp2f)
    return __builtin_amdgcn_exp2f(x);
#else
    return exp2f(x);
#endif
}

__device__ __forceinline__ float fast_rcp(float x) {
#if __has_builtin(__builtin_amdgcn_rcpf)
    return __builtin_amdgcn_rcpf(x);
#else
    return 1.0f / x;
#endif
}

// tanh(x) = 2*sigmoid(2x) - 1 = 2/(1+exp2(-2.885390x)) - 1
__device__ __forceinline__ float fast_tanh(float x) {
    return 2.0f * fast_rcp(1.0f + fast_exp2(-2.88539008f * x)) - 1.0f;
}

template <int CTRL>
__device__ __forceinline__ float dpp_mov(float v) {
    int i = __builtin_bit_cast(int, v);
    i = __builtin_amdgcn_mov_dpp(i, CTRL, 0xF, 0xF, true);
    return __builtin_bit_cast(float, i);
}

#define DPP_QB0         0x00   // quad_perm [0,0,0,0] -> i gate
#define DPP_QB1         0x55   // quad_perm [1,1,1,1] -> f gate
#define DPP_QB2         0xAA   // quad_perm [2,2,2,2] -> g gate
#define DPP_QB3         0xFF   // quad_perm [3,3,3,3] -> o gate
#define DPP_ROR8        0x128  // l^8  -> u^2 (on quad-uniform data)
#define DPP_MIRROR      0x140  // l^15 -> u^3 (on quad-uniform data)
#define DPP_HALF_MIRROR 0x141  // l^7  -> u^1 (on quad-uniform data)

__global__ __launch_bounds__(512) void lstm_r7_kernel(
    const float* __restrict__ x,
    const float* __restrict__ W_ih0, const float* __restrict__ W_hh0,
    const float* __restrict__ b_ih0, const float* __restrict__ b_hh0,
    const float* __restrict__ W_ih1, const float* __restrict__ W_hh1,
    const float* __restrict__ b_ih1, const float* __restrict__ b_hh1,
    const float* __restrict__ W1, const float* __restrict__ b1,
    const float* __restrict__ W2, const float* __restrict__ b2,
    float* __restrict__ out)
{
    // x stage: [pair][slot][ch*17 + step] (pad 17 -> per-chain bank offset, reads conflict-free)
    __shared__ float4 xstage[4][2][68];
    // h0 ring: [pair][slot][step][chain], plain-order h[4] per chain
    __shared__ float4 ring[4][2][CHUNK][4];

    const int tid  = threadIdx.x;
    const int wave = tid >> 6;
    const int stg  = wave >> 2;         // 0 = L0 producer, 1 = L1+head consumer
    const int pr   = wave & 3;          // pair index: A-wave pr and B-wave pr share chains
    const int lane = tid & 63;
    const int idx  = lane & 15;         // lane within 16-lane chain group (also step-slot)
    const int rho  = lane & 3;          // role: 0=i,1=f,2=g,3=o
    const int u    = (lane >> 2) & 3;   // hidden unit
    const int r    = rho * 4 + u;       // gate row in 16-row weight matrices
    const int ch   = lane >> 4;         // chain within pair
    const int batch = blockIdx.x * 16 + pr * 4 + ch;

    // Per-lane activation constants: role g (rho==2) uses tanh = 2*sigma(2x)-1.
    const float am = (rho == 2) ? -2.88539008f : -1.44269504f;
    const float aa = (rho == 2) ? 2.0f : 1.0f;
    const float ab = (rho == 2) ? -1.0f : 0.0f;

    // ---- stage A (layer 0) constants ----
    const float wx0 = W_ih0[r * 3 + 0];
    const float wx1 = W_ih0[r * 3 + 1];
    const float wx2 = W_ih0[r * 3 + 2];
    const float bias0 = b_ih0[r] + b_hh0[r];
    float wh0[4];
#pragma unroll
    for (int k = 0; k < 4; ++k) wh0[k] = W_hh0[r * 4 + (u ^ k)];   // xor order (reg quad)

    // ---- stage B (layer 1 + head) constants ----
    const float bias1 = b_ih1[r] + b_hh1[r];
    float wi1[4], wh1[4], w1p[4];
#pragma unroll
    for (int k = 0; k < 4; ++k) {
        wi1[k] = W_ih1[r * 4 + k];          // PLAIN order (ring h0 is plain)
        wh1[k] = W_hh1[r * 4 + (u ^ k)];    // xor order (register quad)
        w1p[k] = W1[u * 4 + (u ^ k)];       // xor order (register quad)
    }
    const float b1u = b1[u];
    const float w2u = W2[u];
    const float b2v = b2[0];

    // ---- per-stage state ----
    float h0 = 0.f, c0 = 0.f, h0b = 0.f, h0c = 0.f, h0d = 0.f;   // A
    float h1 = 0.f, c1 = 0.f, h1b = 0.f, h1c = 0.f, h1d = 0.f;   // B
    float ysave = 0.f;                                            // B
    float* op = out + (size_t)batch * T_STEPS;

    // A: per-lane x row pointer; lane idx owns step (chunk*16 + idx) of its chain.
    const float* xrow = x + (size_t)batch * T_STEPS * 3;
    float q0 = 0.f, q1 = 0.f, q2 = 0.f;   // staged regs for chunk c+1
    if (stg == 0) {
        // prime: stage chunk 0 into slot 0, load chunk 1 into regs
        const float* p0 = xrow + idx * 3;
        xstage[pr][0][ch * 17 + idx] = make_float4(p0[0], p0[1], p0[2], 0.f);
        const float* p1 = xrow + 48 + idx * 3;
        q0 = p1[0]; q1 = p1[1]; q2 = p1[2];
    }

    for (int c = 0; c <= NCHUNK; ++c) {
        if (stg == 0) {
            if (c < NCHUNK) {
                // ================= stage A: layer 0, chunk c =================
                const int s = c & 1;
                const float4* xs = &xstage[pr][s][ch * 17];
                float4 xc = xs[0];
#pragma unroll
                for (int tt = 0; tt < CHUNK; ++tt) {
                    float4 xn = xs[(tt < CHUNK - 1) ? tt + 1 : tt];   // 1-step LDS prefetch

                    float pre0 = bias0 + wx0 * xc.x + wx1 * xc.y + wx2 * xc.z
                               + wh0[0] * h0 + wh0[1] * h0b + wh0[2] * h0c + wh0[3] * h0d;
                    float a0 = aa * fast_rcp(1.0f + fast_exp2(am * pre0)) + ab;
                    float gi = dpp_mov<DPP_QB0>(a0);
                    float gf = dpp_mov<DPP_QB1>(a0);
                    float gg = dpp_mov<DPP_QB2>(a0);
                    float go = dpp_mov<DPP_QB3>(a0);
                    c0 = gf * c0 + gi * gg;
                    h0 = go * fast_tanh(c0);
                    h0b = dpp_mov<DPP_HALF_MIRROR>(h0);
                    h0c = dpp_mov<DPP_ROR8>(h0);
                    h0d = dpp_mov<DPP_MIRROR>(h0);

                    if (rho == 0) ((float*)&ring[pr][s][tt][ch])[u] = h0;  // plain h0[u]
                    xc = xn;
                }
                // stage chunk c+1 (regs loaded last iteration), prefetch chunk c+2
                if (c < NCHUNK - 1)
                    xstage[pr][(c + 1) & 1][ch * 17 + idx] = make_float4(q0, q1, q2, 0.f);
                if (c < NCHUNK - 2) {
                    const float* p = xrow + (c + 2) * 48 + idx * 3;
                    q0 = p[0]; q1 = p[1]; q2 = p[2];
                }
            }
        } else if (c >= 1) {
            // ========== stage B: layer 1 + head, chunk c-1 ==========
            const int cc = c - 1;
            const int s = cc & 1;
            const float4* rgp = &ring[pr][s][0][ch];   // step stride = 4 float4s
            float4 h_a = rgp[0];
            float4 h_b = rgp[4];
#pragma unroll
            for (int tt = 0; tt < CHUNK; ++tt) {
                // 2-step LDS prefetch (clamped; dead value near chunk end)
                float4 h_n = rgp[4 * ((tt < CHUNK - 2) ? tt + 2 : CHUNK - 1)];

                float pre1 = bias1
                           + wi1[0] * h_a.x + wi1[1] * h_a.y
                           + wi1[2] * h_a.z + wi1[3] * h_a.w
                           + wh1[0] * h1 + wh1[1] * h1b + wh1[2] * h1c + wh1[3] * h1d;
                float a1 = aa * fast_rcp(1.0f + fast_exp2(am * pre1)) + ab;
                float gi1 = dpp_mov<DPP_QB0>(a1);
                float gf1 = dpp_mov<DPP_QB1>(a1);
                float gg1 = dpp_mov<DPP_QB2>(a1);
                float go1 = dpp_mov<DPP_QB3>(a1);
                c1 = gf1 * c1 + gi1 * gg1;
                h1 = go1 * fast_tanh(c1);
                h1b = dpp_mov<DPP_HALF_MIRROR>(h1);
                h1c = dpp_mov<DPP_ROR8>(h1);
                h1d = dpp_mov<DPP_MIRROR>(h1);

                // head: y = W2 . tanh(W1 h1 + b1) + b2
                float zp = b1u + w1p[0] * h1 + w1p[1] * h1b + w1p[2] * h1c + w1p[3] * h1d;
                float z  = fast_tanh(zp);
                float yv = w2u * z;                              // quad-uniform
                float t1 = yv + dpp_mov<DPP_ROR8>(yv);           // + unit u^2
                float y  = t1 + dpp_mov<DPP_MIRROR>(t1) + b2v;   // + units u^1,u^3

                ysave = (tt == idx) ? y : ysave;
                h_a = h_b; h_b = h_n;
            }
            op[cc * CHUNK + idx] = ysave;   // 16 consecutive floats per chain: coalesced
        }
        __syncthreads();
    }
}

extern "C" void kernel_launch(void* const* d_in, const int* in_sizes, int n_in,
                              void* d_out, int out_size, void* d_ws, size_t ws_size,
                              hipStream_t stream) {
    const float* x     = (const float*)d_in[0];
    const float* W_ih0 = (const float*)d_in[1];
    const float* W_hh0 = (const float*)d_in[2];
    const float* b_ih0 = (const float*)d_in[3];
    const float* b_hh0 = (const float*)d_in[4];
    const float* W_ih1 = (const float*)d_in[5];
    const float* W_hh1 = (const float*)d_in[6];
    const float* b_ih1 = (const float*)d_in[7];
    const float* b_hh1 = (const float*)d_in[8];
    const float* W1    = (const float*)d_in[9];
    const float* b1    = (const float*)d_in[10];
    const float* W2    = (const float*)d_in[11];
    const float* b2    = (const float*)d_in[12];
    float* out = (float*)d_out;

    dim3 grid(BATCH / 16);   // 256 blocks = 1 per CU, 16 chains each
    dim3 block(512);         // 8 waves: 4x stage-A (pr 0..3) + 4x stage-B (pr 0..3)
    lstm_r7_kernel<<<grid, block, 0, stream>>>(
        x, W_ih0, W_hh0, b_ih0, b_hh0, W_ih1, W_hh1, b_ih1, b_hh1,
        W1, b1, W2, b2, out);
}

// Round 8
// 247.385 us; speedup vs baseline: 1.1380x; 1.0205x over previous
//
#include <hip/hip_runtime.h>

// MyLSTM: 2-layer LSTM (input=3, hidden=4) + MLP head (4->4 tanh -> 1), B=4096, T=1024.
//
// R8 = R7 (177 us, 82% VALUBusy) with the chunk __syncthreads replaced by a flag-based
// producer/consumer credit ring (depth 4). R7's residual 18% stall is barrier coupling:
// all 8 waves lock to the slowest stage each chunk (B ~130 cyc/step vs A ~100), so A
// idles at every barrier. With flags, A free-runs up to 4 chunks ahead (throttled only
// by ring credit) and B polls a wave-uniform LDS flag (broadcast ds_read + s_sleep);
// a polling wave issues ~nothing, donating its SIMD issue slots to its partner.
// LDS ordering: per-wave LDS pipeline is in-order; __threadfence_block() between ring
// data writes and the done-flag write. Flags are monotonic chunk counters (no ABA).
// Cell math is byte-identical to R7 (absmax must stay 0.001953125).
//
// Topology (from R7): block=512, 8 waves; stage = wave>>2 (0=L0 producer, 1=L1+head
// consumer), pair = wave&3; HW round-robins waves to SIMD w%4 -> every SIMD gets
// exactly one A and one B wave. 16 lanes/chain, 4 chains/wave; DPP-only cross-lane.

#define T_STEPS 1024
#define BATCH   4096
#define CHUNK   16
#define NCHUNK  (T_STEPS / CHUNK)
#define RDEPTH  4   // ring depth in chunks (power of 2)

__device__ __forceinline__ float fast_exp2(float x) {
#if __has_builtin(__builtin_amdgcn_exp2f)
    return __builtin_amdgcn_exp2f(x);
#else
    return exp2f(x);
#endif
}

__device__ __forceinline__ float fast_rcp(float x) {
#if __has_builtin(__builtin_amdgcn_rcpf)
    return __builtin_amdgcn_rcpf(x);
#else
    return 1.0f / x;
#endif
}

// tanh(x) = 2*sigmoid(2x) - 1 = 2/(1+exp2(-2.885390x)) - 1
__device__ __forceinline__ float fast_tanh(float x) {
    return 2.0f * fast_rcp(1.0f + fast_exp2(-2.88539008f * x)) - 1.0f;
}

template <int CTRL>
__device__ __forceinline__ float dpp_mov(float v) {
    int i = __builtin_bit_cast(int, v);
    i = __builtin_amdgcn_mov_dpp(i, CTRL, 0xF, 0xF, true);
    return __builtin_bit_cast(float, i);
}

#define DPP_QB0         0x00   // quad_perm [0,0,0,0] -> i gate
#define DPP_QB1         0x55   // quad_perm [1,1,1,1] -> f gate
#define DPP_QB2         0xAA   // quad_perm [2,2,2,2] -> g gate
#define DPP_QB3         0xFF   // quad_perm [3,3,3,3] -> o gate
#define DPP_ROR8        0x128  // l^8  -> u^2 (on quad-uniform data)
#define DPP_MIRROR      0x140  // l^15 -> u^3 (on quad-uniform data)
#define DPP_HALF_MIRROR 0x141  // l^7  -> u^1 (on quad-uniform data)

__global__ __launch_bounds__(512) void lstm_r8_kernel(
    const float* __restrict__ x,
    const float* __restrict__ W_ih0, const float* __restrict__ W_hh0,
    const float* __restrict__ b_ih0, const float* __restrict__ b_hh0,
    const float* __restrict__ W_ih1, const float* __restrict__ W_hh1,
    const float* __restrict__ b_ih1, const float* __restrict__ b_hh1,
    const float* __restrict__ W1, const float* __restrict__ b1,
    const float* __restrict__ W2, const float* __restrict__ b2,
    float* __restrict__ out)
{
    // x stage: [pair][slot][ch*17 + step] (A-private, self-ordered; +17 pad)
    __shared__ float4 xstage[4][2][68];
    // h0 ring: [pair][slot][step][chain], plain-order h[4] per chain (16 KB)
    __shared__ float4 ring[4][RDEPTH][CHUNK][4];
    // monotonic chunk counters: done = producer wrote chunk c (value c+1);
    // freed = consumer finished chunk c (value c+1)
    __shared__ int done_flag[4][RDEPTH];
    __shared__ int free_flag[4][RDEPTH];

    const int tid  = threadIdx.x;
    const int wave = tid >> 6;
    const int stg  = wave >> 2;         // 0 = L0 producer, 1 = L1+head consumer
    const int pr   = wave & 3;          // pair index: A-wave pr and B-wave pr share chains
    const int lane = tid & 63;
    const int idx  = lane & 15;         // lane within 16-lane chain group (also step-slot)
    const int rho  = lane & 3;          // role: 0=i,1=f,2=g,3=o
    const int u    = (lane >> 2) & 3;   // hidden unit
    const int r    = rho * 4 + u;       // gate row in 16-row weight matrices
    const int ch   = lane >> 4;         // chain within pair
    const int batch = blockIdx.x * 16 + pr * 4 + ch;

    // init flags, one barrier total (outside hot loop)
    if (tid < 4 * RDEPTH) {
        done_flag[tid >> 2][tid & 3] = 0;
        free_flag[tid >> 2][tid & 3] = 0;
    }
    __syncthreads();

    // Per-lane activation constants: role g (rho==2) uses tanh = 2*sigma(2x)-1.
    const float am = (rho == 2) ? -2.88539008f : -1.44269504f;
    const float aa = (rho == 2) ? 2.0f : 1.0f;
    const float ab = (rho == 2) ? -1.0f : 0.0f;

    if (stg == 0) {
        // ======================= stage A: layer 0 producer =======================
        const float wx0 = W_ih0[r * 3 + 0];
        const float wx1 = W_ih0[r * 3 + 1];
        const float wx2 = W_ih0[r * 3 + 2];
        const float bias0 = b_ih0[r] + b_hh0[r];
        float wh0[4];
#pragma unroll
        for (int k = 0; k < 4; ++k) wh0[k] = W_hh0[r * 4 + (u ^ k)];   // xor order

        float h0 = 0.f, c0 = 0.f, h0b = 0.f, h0c = 0.f, h0d = 0.f;

        const float* xrow = x + (size_t)batch * T_STEPS * 3;
        // prime: stage chunk 0 into x-slot 0, load chunk 1 into regs
        const float* p0 = xrow + idx * 3;
        xstage[pr][0][ch * 17 + idx] = make_float4(p0[0], p0[1], p0[2], 0.f);
        const float* p1 = xrow + 48 + idx * 3;
        float q0 = p1[0], q1 = p1[1], q2 = p1[2];

        volatile int* ff = &free_flag[pr][0];

        for (int c = 0; c < NCHUNK; ++c) {
            const int s = c & (RDEPTH - 1);
            // ring credit: previous occupant of slot s was chunk c-RDEPTH
            if (c >= RDEPTH) {
                while (ff[s] < c - RDEPTH + 1) { __builtin_amdgcn_s_sleep(1); }
            }

            const float4* xs = &xstage[pr][c & 1][ch * 17];
            float4 xc = xs[0];
#pragma unroll
            for (int tt = 0; tt < CHUNK; ++tt) {
                float4 xn = xs[(tt < CHUNK - 1) ? tt + 1 : tt];   // 1-step LDS prefetch

                float pre0 = bias0 + wx0 * xc.x + wx1 * xc.y + wx2 * xc.z
                           + wh0[0] * h0 + wh0[1] * h0b + wh0[2] * h0c + wh0[3] * h0d;
                float a0 = aa * fast_rcp(1.0f + fast_exp2(am * pre0)) + ab;
                float gi = dpp_mov<DPP_QB0>(a0);
                float gf = dpp_mov<DPP_QB1>(a0);
                float gg = dpp_mov<DPP_QB2>(a0);
                float go = dpp_mov<DPP_QB3>(a0);
                c0 = gf * c0 + gi * gg;
                h0 = go * fast_tanh(c0);
                h0b = dpp_mov<DPP_HALF_MIRROR>(h0);
                h0c = dpp_mov<DPP_ROR8>(h0);
                h0d = dpp_mov<DPP_MIRROR>(h0);

                if (rho == 0) ((float*)&ring[pr][s][tt][ch])[u] = h0;  // plain h0[u]
                xc = xn;
            }
            // publish chunk c
            __threadfence_block();
            if (lane == 0) done_flag[pr][s] = c + 1;

            // stage chunk c+1 (regs loaded last chunk), prefetch chunk c+2
            if (c < NCHUNK - 1)
                xstage[pr][(c + 1) & 1][ch * 17 + idx] = make_float4(q0, q1, q2, 0.f);
            if (c < NCHUNK - 2) {
                const float* p = xrow + (c + 2) * 48 + idx * 3;
                q0 = p[0]; q1 = p[1]; q2 = p[2];
            }
        }
    } else {
        // =================== stage B: layer 1 + head consumer ===================
        const float bias1 = b_ih1[r] + b_hh1[r];
        float wi1[4], wh1[4], w1p[4];
#pragma unroll
        for (int k = 0; k < 4; ++k) {
            wi1[k] = W_ih1[r * 4 + k];          // PLAIN order (ring h0 is plain)
            wh1[k] = W_hh1[r * 4 + (u ^ k)];    // xor order (register quad)
            w1p[k] = W1[u * 4 + (u ^ k)];       // xor order (register quad)
        }
        const float b1u = b1[u];
        const float w2u = W2[u];
        const float b2v = b2[0];

        float h1 = 0.f, c1 = 0.f, h1b = 0.f, h1c = 0.f, h1d = 0.f;
        float ysave = 0.f;
        float* op = out + (size_t)batch * T_STEPS;

        volatile int* df = &done_flag[pr][0];

        for (int c = 0; c < NCHUNK; ++c) {
            const int s = c & (RDEPTH - 1);
            while (df[s] < c + 1) { __builtin_amdgcn_s_sleep(1); }
            __threadfence_block();

            const float4* rgp = &ring[pr][s][0][ch];   // step stride = 4 float4s
            float4 h_a = rgp[0];
            float4 h_b = rgp[4];
#pragma unroll
            for (int tt = 0; tt < CHUNK; ++tt) {
                // 2-step LDS prefetch (clamped; dead value near chunk end)
                float4 h_n = rgp[4 * ((tt < CHUNK - 2) ? tt + 2 : CHUNK - 1)];

                float pre1 = bias1
                           + wi1[0] * h_a.x + wi1[1] * h_a.y
                           + wi1[2] * h_a.z + wi1[3] * h_a.w
                           + wh1[0] * h1 + wh1[1] * h1b + wh1[2] * h1c + wh1[3] * h1d;
                float a1 = aa * fast_rcp(1.0f + fast_exp2(am * pre1)) + ab;
                float gi1 = dpp_mov<DPP_QB0>(a1);
                float gf1 = dpp_mov<DPP_QB1>(a1);
                float gg1 = dpp_mov<DPP_QB2>(a1);
                float go1 = dpp_mov<DPP_QB3>(a1);
                c1 = gf1 * c1 + gi1 * gg1;
                h1 = go1 * fast_tanh(c1);
                h1b = dpp_mov<DPP_HALF_MIRROR>(h1);
                h1c = dpp_mov<DPP_ROR8>(h1);
                h1d = dpp_mov<DPP_MIRROR>(h1);

                // head: y = W2 . tanh(W1 h1 + b1) + b2
                float zp = b1u + w1p[0] * h1 + w1p[1] * h1b + w1p[2] * h1c + w1p[3] * h1d;
                float z  = fast_tanh(zp);
                float yv = w2u * z;                              // quad-uniform
                float t1 = yv + dpp_mov<DPP_ROR8>(yv);           // + unit u^2
                float y  = t1 + dpp_mov<DPP_MIRROR>(t1) + b2v;   // + units u^1,u^3

                ysave = (tt == idx) ? y : ysave;
                h_a = h_b; h_b = h_n;
            }
            // release slot s, then store the chunk's outputs (coalesced 16 floats/chain)
            if (lane == 0) free_flag[pr][s] = c + 1;
            op[c * CHUNK + idx] = ysave;
        }
    }
}

extern "C" void kernel_launch(void* const* d_in, const int* in_sizes, int n_in,
                              void* d_out, int out_size, void* d_ws, size_t ws_size,
                              hipStream_t stream) {
    const float* x     = (const float*)d_in[0];
    const float* W_ih0 = (const float*)d_in[1];
    const float* W_hh0 = (const float*)d_in[2];
    const float* b_ih0 = (const float*)d_in[3];
    const float* b_hh0 = (const float*)d_in[4];
    const float* W_ih1 = (const float*)d_in[5];
    const float* W_hh1 = (const float*)d_in[6];
    const float* b_ih1 = (const float*)d_in[7];
    const float* b_hh1 = (const float*)d_in[8];
    const float* W1    = (const float*)d_in[9];
    const float* b1    = (const float*)d_in[10];
    const float* W2    = (const float*)d_in[11];
    const float* b2    = (const float*)d_in[12];
    float* out = (float*)d_out;

    dim3 grid(BATCH / 16);   // 256 blocks = 1 per CU, 16 chains each
    dim3 block(512);         // 8 waves: 4x stage-A (pr 0..3) + 4x stage-B (pr 0..3)
    lstm_r8_kernel<<<grid, block, 0, stream>>>(
        x, W_ih0, W_hh0, b_ih0, b_hh0, W_ih1, W_hh1, b_ih1, b_hh1,
        W1, b1, W2, b2, out);
}